// Round 4
// baseline (551.466 us; speedup 1.0000x reference)
//
#include <hip/hip_runtime.h>

#define NPTS 65536
#define INC  256
#define MID  64
#define KNB  16
#define WSTR 72   // padded LDS row stride (shorts)

typedef __attribute__((ext_vector_type(8))) short short8;
typedef __attribute__((ext_vector_type(4))) float f32x4;

#define MFMA(a, b, c) __builtin_amdgcn_mfma_f32_16x16x32_bf16((a), (b), (c), 0, 0, 0)

__device__ inline short f2bf(float f) {
    unsigned int u = __builtin_bit_cast(unsigned int, f);
    unsigned int r = (u + 0x7fffu + ((u >> 16) & 1u)) >> 16;
    return (short)r;
}
__device__ inline float bf2f(unsigned short s) {
    unsigned int u = ((unsigned int)s) << 16;
    return __builtin_bit_cast(float, u);
}
__device__ inline short8 cvtf8(f32x4 a, f32x4 b) {
    short8 r;
    r[0] = f2bf(a[0]); r[1] = f2bf(a[1]); r[2] = f2bf(a[2]); r[3] = f2bf(a[3]);
    r[4] = f2bf(b[0]); r[5] = f2bf(b[1]); r[6] = f2bf(b[2]); r[7] = f2bf(b[3]);
    return r;
}
__device__ inline short8 load_cvt8(const float* __restrict__ p) {
    const f32x4* v = (const f32x4*)p;
    f32x4 a = v[0], b = v[1];
    return cvtf8(a, b);
}

// Stage one B-fragment entry of a [64 x 64] row-major matrix into LDS.
// entry e (0..511): f = e>>6 (frag: nt = f&3, ks = f>>2), ln = e&63.
__device__ inline void fill_frag64(short* dst, const float* __restrict__ src, int e) {
    int f = e >> 6, ln = e & 63;
    int nt = f & 3, ks = f >> 2;
    int row = nt * 16 + (ln & 15), col = ks * 32 + (ln >> 4) * 8;
    *(short8*)&dst[(size_t)e * 8] = load_cvt8(src + (size_t)row * MID + col);
}

// ---------------------------------------------------------------------------
// Kernel 1: xx = feats @ w_in.T ; q/k/v = xx @ w_{q,k,v}.T + b
// block = 256 (4 waves x 16 rows = 64 rows); grid = 1024 (2 blocks/CU)
// w_in (32 KB) + wq/wk/wv (24 KB) as bf16 fragments in LDS; q stored bf16
// ---------------------------------------------------------------------------
__global__ __launch_bounds__(256, 2) void k_qkv(
    const float* __restrict__ feats, const float* __restrict__ w_in,
    const float* __restrict__ w_q, const float* __restrict__ b_q,
    const float* __restrict__ w_k, const float* __restrict__ b_k,
    const float* __restrict__ w_v, const float* __restrict__ b_v,
    short* __restrict__ q_out, short* __restrict__ k_out, short* __restrict__ v_out)
{
    __shared__ __align__(16) short WIN[2048 * 8];     // 32 KB: w_in frags (ks 0..7, nt 0..3)
    __shared__ __align__(16) short BW[3 * 512 * 8];   // 24 KB: wq|wk|wv frags
    __shared__ __align__(16) short XL[4][16 * WSTR];  // 9.2 KB
    const int tid = threadIdx.x;
    const int wave = tid >> 6, lane = tid & 63;
    const int l15 = lane & 15, quad = lane >> 4;

    // stage w_in: 2048 entries (f = ks*4+nt, ks 0..7)
    #pragma unroll
    for (int rep = 0; rep < 8; rep++) {
        int e = rep * 256 + tid;
        int f = e >> 6, ln = e & 63;
        int nt = f & 3, ks = f >> 2;
        int row = nt * 16 + (ln & 15), col = ks * 32 + (ln >> 4) * 8;
        *(short8*)&WIN[(size_t)e * 8] = load_cvt8(w_in + (size_t)row * INC + col);
    }
    // stage wq / wk / wv (no pointer arrays -> no stack)
    #pragma unroll
    for (int rep = 0; rep < 2; rep++) fill_frag64(BW,            w_q, rep * 256 + tid);
    #pragma unroll
    for (int rep = 0; rep < 2; rep++) fill_frag64(BW + 4096,     w_k, rep * 256 + tid);
    #pragma unroll
    for (int rep = 0; rep < 2; rep++) fill_frag64(BW + 8192,     w_v, rep * 256 + tid);
    __syncthreads();

    const int rb = (blockIdx.x * 4 + wave) * 16;

    float biasq[4], biask[4], biasv[4];
    #pragma unroll
    for (int nt = 0; nt < 4; nt++) {
        biasq[nt] = b_q[nt * 16 + l15];
        biask[nt] = b_k[nt * 16 + l15];
        biasv[nt] = b_v[nt * 16 + l15];
    }

    // xx = feats @ w_in.T  (A from global fp32->bf16, B from LDS)
    f32x4 acc[4];
    #pragma unroll
    for (int nt = 0; nt < 4; nt++) acc[nt] = (f32x4){0.f, 0.f, 0.f, 0.f};
    const float* arow = feats + (size_t)(rb + l15) * INC + quad * 8;
    #pragma unroll
    for (int ks = 0; ks < 8; ks++) {
        short8 a = load_cvt8(arow + ks * 32);
        #pragma unroll
        for (int nt = 0; nt < 4; nt++) {
            short8 b = *(const short8*)&WIN[(size_t)((ks * 4 + nt) * 64 + lane) * 8];
            acc[nt] = MFMA(a, b, acc[nt]);
        }
    }
    #pragma unroll
    for (int nt = 0; nt < 4; nt++)
        #pragma unroll
        for (int r = 0; r < 4; r++)
            XL[wave][(quad * 4 + r) * WSTR + nt * 16 + l15] = f2bf(acc[nt][r]);

    short8 a0 = *(const short8*)&XL[wave][l15 * WSTR + quad * 8];
    short8 a1 = *(const short8*)&XL[wave][l15 * WSTR + 32 + quad * 8];

    // Q (bf16 out)
    #pragma unroll
    for (int nt = 0; nt < 4; nt++) {
        short8 b0 = *(const short8*)&BW[(size_t)((0 + nt) * 64 + lane) * 8];
        short8 b1 = *(const short8*)&BW[(size_t)((4 + nt) * 64 + lane) * 8];
        f32x4 c = (f32x4){0.f, 0.f, 0.f, 0.f};
        c = MFMA(a0, b0, c); c = MFMA(a1, b1, c);
        #pragma unroll
        for (int r = 0; r < 4; r++)
            q_out[(size_t)(rb + quad * 4 + r) * MID + nt * 16 + l15] = f2bf(c[r] + biasq[nt]);
    }
    // K
    #pragma unroll
    for (int nt = 0; nt < 4; nt++) {
        short8 b0 = *(const short8*)&BW[4096 + (size_t)((0 + nt) * 64 + lane) * 8];
        short8 b1 = *(const short8*)&BW[4096 + (size_t)((4 + nt) * 64 + lane) * 8];
        f32x4 c = (f32x4){0.f, 0.f, 0.f, 0.f};
        c = MFMA(a0, b0, c); c = MFMA(a1, b1, c);
        #pragma unroll
        for (int r = 0; r < 4; r++)
            k_out[(size_t)(rb + quad * 4 + r) * MID + nt * 16 + l15] = f2bf(c[r] + biask[nt]);
    }
    // V
    #pragma unroll
    for (int nt = 0; nt < 4; nt++) {
        short8 b0 = *(const short8*)&BW[8192 + (size_t)((0 + nt) * 64 + lane) * 8];
        short8 b1 = *(const short8*)&BW[8192 + (size_t)((4 + nt) * 64 + lane) * 8];
        f32x4 c = (f32x4){0.f, 0.f, 0.f, 0.f};
        c = MFMA(a0, b0, c); c = MFMA(a1, b1, c);
        #pragma unroll
        for (int r = 0; r < 4; r++)
            v_out[(size_t)(rb + quad * 4 + r) * MID + nt * 16 + l15] = f2bf(c[r] + biasv[nt]);
    }
}

// ---------------------------------------------------------------------------
// Kernel 2: per-point attention. block = 512 (8 waves); 4 points per wave
// (staged once, processed sequentially); grid = 2048. LDS ~45 KB -> 3 blk/CU.
// ---------------------------------------------------------------------------
__global__ __launch_bounds__(512, 4) void k_attn(
    const float* __restrict__ pos, const int* __restrict__ idx,
    const unsigned short* __restrict__ q_bf, const unsigned short* __restrict__ k_bf,
    const unsigned short* __restrict__ v_bf,
    const float* __restrict__ pe_w1, const float* __restrict__ pe_b1,
    const float* __restrict__ pe_g1, const float* __restrict__ pe_be1,
    const float* __restrict__ pe_m1, const float* __restrict__ pe_v1,
    const float* __restrict__ pe_w2, const float* __restrict__ pe_b2,
    const float* __restrict__ pe_g2, const float* __restrict__ pe_be2,
    const float* __restrict__ pe_m2, const float* __restrict__ pe_v2,
    const float* __restrict__ ga_w1, const float* __restrict__ ga_b1,
    const float* __restrict__ ga_g1, const float* __restrict__ ga_be1,
    const float* __restrict__ ga_m1, const float* __restrict__ ga_v1,
    const float* __restrict__ ga_w2, const float* __restrict__ ga_b2,
    const float* __restrict__ ga_g2, const float* __restrict__ ga_be2,
    const float* __restrict__ ga_m2, const float* __restrict__ ga_v2,
    short* __restrict__ om_bf)
{
    __shared__ __align__(16) short BW[2 * 512 * 8];   // 16 KB: ga_w1|ga_w2 frags
    __shared__ __align__(16) short Wb[8][16 * WSTR];  // 18.4 KB activation tiles
    __shared__ float PS[8][64 * 4];                   // PE1 outputs, 4 pts x 16 nb (8 KB)
    __shared__ int   JI[8][64];                       // neighbor indices (2 KB)

    const int tid = threadIdx.x;
    const int wave = tid >> 6, lane = tid & 63;
    const int l15 = lane & 15, quad = lane >> 4;

    #pragma unroll
    for (int rep = 0; rep < 2; rep++) fill_frag64(BW,        ga_w1, rep * 512 + tid - (rep ? 512 : 0) + rep * 512);
    // (the expression above is just rep*512+tid folded; keep simple below)
    __syncthreads(); // cheap; re-stage correctly (idempotent writes)
    #pragma unroll
    for (int rep = 0; rep < 1; rep++) { fill_frag64(BW, ga_w1, tid); }
    { fill_frag64(BW + 4096, ga_w2, tid); }
    __syncthreads();

    // folded constants
    float w20 = pe_w2[lane * 3 + 0], w21 = pe_w2[lane * 3 + 1], w22 = pe_w2[lane * 3 + 2];
    float s2  = pe_g2[lane] * rsqrtf(pe_v2[lane] + 1e-5f);
    float sh2 = (pe_b2[lane] - pe_m2[lane]) * s2 + pe_be2[lane];

    float pw00, pw01, pw02, pw03, pw10, pw11, pw12, pw13, pw20_, pw21_, pw22_, pw23;
    {
        float s0 = pe_g1[0] * rsqrtf(pe_v1[0] + 1e-5f);
        float s1 = pe_g1[1] * rsqrtf(pe_v1[1] + 1e-5f);
        float sC = pe_g1[2] * rsqrtf(pe_v1[2] + 1e-5f);
        pw00 = pe_w1[0] * s0; pw01 = pe_w1[1] * s0; pw02 = pe_w1[2] * s0;
        pw03 = (pe_b1[0] - pe_m1[0]) * s0 + pe_be1[0];
        pw10 = pe_w1[3] * s1; pw11 = pe_w1[4] * s1; pw12 = pe_w1[5] * s1;
        pw13 = (pe_b1[1] - pe_m1[1]) * s1 + pe_be1[1];
        pw20_ = pe_w1[6] * sC; pw21_ = pe_w1[7] * sC; pw22_ = pe_w1[8] * sC;
        pw23 = (pe_b1[2] - pe_m1[2]) * sC + pe_be1[2];
    }

    float gs1[4], gh1[4], gs2[4], gh2[4];
    #pragma unroll
    for (int nt = 0; nt < 4; nt++) {
        int o = nt * 16 + l15;
        gs1[nt] = ga_g1[o] * rsqrtf(ga_v1[o] + 1e-5f);
        gh1[nt] = (ga_b1[o] - ga_m1[o]) * gs1[nt] + ga_be1[o];
        gs2[nt] = ga_g2[o] * rsqrtf(ga_v2[o] + 1e-5f);
        gh2[nt] = (ga_b2[o] - ga_m2[o]) * gs2[nt] + ga_be2[o];
    }

    const int n0 = (blockIdx.x * 8 + wave) * 4;   // first of 4 points

    // stage 4 points at once: lane -> (pt = lane>>4, nb = lane&15)
    {
        int m = idx[(size_t)n0 * KNB + lane];     // 64 contiguous ints, coalesced
        JI[wave][lane] = m;
        float px = pos[(size_t)m * 3 + 0];
        float py = pos[(size_t)m * 3 + 1];
        float pz = pos[(size_t)m * 3 + 2];
        PS[wave][lane * 4 + 0] = fmaxf(px * pw00 + py * pw01 + pz * pw02 + pw03, 0.f);
        PS[wave][lane * 4 + 1] = fmaxf(px * pw10 + py * pw11 + pz * pw12 + pw13, 0.f);
        PS[wave][lane * 4 + 2] = fmaxf(px * pw20_ + py * pw21_ + pz * pw22_ + pw23, 0.f);
    }
    // same-wave LDS ops are in-order: no barrier needed before reads below

    #pragma unroll 1
    for (int it = 0; it < 4; it++) {
        const int n = n0 + it;
        const int base = it * KNB;
        float qv = bf2f(q_bf[(size_t)n * MID + lane]);

        int mj[KNB];
        #pragma unroll
        for (int j = 0; j < KNB; j++) mj[j] = JI[wave][base + j];

        // gather k in 2 batches of 8; build w = xk - q + p  (lane = channel)
        #pragma unroll
        for (int h = 0; h < 2; h++) {
            unsigned short kr[8];
            #pragma unroll
            for (int j = 0; j < 8; j++)
                kr[j] = k_bf[(size_t)mj[h * 8 + j] * MID + lane];
            #pragma unroll
            for (int j = 0; j < 8; j++) {
                int r = h * 8 + j;
                float p0 = PS[wave][(base + r) * 4 + 0];
                float p1 = PS[wave][(base + r) * 4 + 1];
                float p2 = PS[wave][(base + r) * 4 + 2];
                float d = p0 * w20 + p1 * w21 + p2 * w22;
                float p = fmaxf(d * s2 + sh2, 0.f);
                Wb[wave][r * WSTR + lane] = f2bf(bf2f(kr[j]) - qv + p);
            }
        }

        // mlp_gamma layer 1
        short8 a0 = *(const short8*)&Wb[wave][l15 * WSTR + quad * 8];
        short8 a1 = *(const short8*)&Wb[wave][l15 * WSTR + 32 + quad * 8];
        #pragma unroll
        for (int nt = 0; nt < 4; nt++) {
            short8 b0 = *(const short8*)&BW[(size_t)((0 + nt) * 64 + lane) * 8];
            short8 b1 = *(const short8*)&BW[(size_t)((4 + nt) * 64 + lane) * 8];
            f32x4 c = (f32x4){0.f, 0.f, 0.f, 0.f};
            c = MFMA(a0, b0, c); c = MFMA(a1, b1, c);
            #pragma unroll
            for (int r = 0; r < 4; r++)
                Wb[wave][(quad * 4 + r) * WSTR + nt * 16 + l15] =
                    f2bf(fmaxf(c[r] * gs1[nt] + gh1[nt], 0.f));
        }

        // mlp_gamma layer 2
        short8 c0 = *(const short8*)&Wb[wave][l15 * WSTR + quad * 8];
        short8 c1 = *(const short8*)&Wb[wave][l15 * WSTR + 32 + quad * 8];
        float sm[4][4];
        #pragma unroll
        for (int nt = 0; nt < 4; nt++) {
            short8 b0 = *(const short8*)&BW[4096 + (size_t)((0 + nt) * 64 + lane) * 8];
            short8 b1 = *(const short8*)&BW[4096 + (size_t)((4 + nt) * 64 + lane) * 8];
            f32x4 c = (f32x4){0.f, 0.f, 0.f, 0.f};
            c = MFMA(c0, b0, c); c = MFMA(c1, b1, c);
            #pragma unroll
            for (int r = 0; r < 4; r++)
                sm[nt][r] = fmaxf(c[r] * gs2[nt] + gh2[nt], 0.f);
        }

        // softmax over 16 neighbors per channel; weights back into Wb (bf16)
        #pragma unroll
        for (int nt = 0; nt < 4; nt++) {
            float mx = fmaxf(fmaxf(sm[nt][0], sm[nt][1]), fmaxf(sm[nt][2], sm[nt][3]));
            mx = fmaxf(mx, __shfl_xor(mx, 16));
            mx = fmaxf(mx, __shfl_xor(mx, 32));
            float e0 = __expf(sm[nt][0] - mx), e1 = __expf(sm[nt][1] - mx);
            float e2 = __expf(sm[nt][2] - mx), e3 = __expf(sm[nt][3] - mx);
            float s = e0 + e1 + e2 + e3;
            s += __shfl_xor(s, 16);
            s += __shfl_xor(s, 32);
            float inv = 1.0f / s;
            Wb[wave][(quad * 4 + 0) * WSTR + nt * 16 + l15] = f2bf(e0 * inv);
            Wb[wave][(quad * 4 + 1) * WSTR + nt * 16 + l15] = f2bf(e1 * inv);
            Wb[wave][(quad * 4 + 2) * WSTR + nt * 16 + l15] = f2bf(e2 * inv);
            Wb[wave][(quad * 4 + 3) * WSTR + nt * 16 + l15] = f2bf(e3 * inv);
        }

        // weighted sum: gather v AFTER softmax (short live range), p recomputed
        float oacc = 0.f;
        #pragma unroll
        for (int h = 0; h < 2; h++) {
            unsigned short vr[8];
            #pragma unroll
            for (int j = 0; j < 8; j++)
                vr[j] = v_bf[(size_t)mj[h * 8 + j] * MID + lane];
            #pragma unroll
            for (int j = 0; j < 8; j++) {
                int r = h * 8 + j;
                float p0 = PS[wave][(base + r) * 4 + 0];
                float p1 = PS[wave][(base + r) * 4 + 1];
                float p2 = PS[wave][(base + r) * 4 + 2];
                float d = p0 * w20 + p1 * w21 + p2 * w22;
                float p = fmaxf(d * s2 + sh2, 0.f);
                oacc += (bf2f(vr[j]) + p) * bf2f((unsigned short)Wb[wave][r * WSTR + lane]);
            }
        }
        om_bf[(size_t)n * MID + lane] = f2bf(oacc);
    }
}

// ---------------------------------------------------------------------------
// Kernel 3: out = out_mid @ w_out.T + feats   [N,64]@[64,256]
// block = 256 (4 waves x 16 rows = 64 rows); grid = 1024. w_out in LDS (32 KB).
// ---------------------------------------------------------------------------
__global__ __launch_bounds__(256, 4) void k_out(
    const unsigned short* __restrict__ om_bf, const float* __restrict__ w_out,
    const float* __restrict__ feats, float* __restrict__ out)
{
    __shared__ __align__(16) short BW[2048 * 8];      // 32 KB: w_out frags (nt 0..15, ks 0..1)
    const int tid = threadIdx.x;
    const int wave = tid >> 6, lane = tid & 63;
    const int l15 = lane & 15, quad = lane >> 4;

    #pragma unroll
    for (int rep = 0; rep < 8; rep++) {
        int e = rep * 256 + tid;
        int f = e >> 6, ln = e & 63;
        int nt = f >> 1, ks = f & 1;
        int row = nt * 16 + (ln & 15), col = ks * 32 + (ln >> 4) * 8;
        *(short8*)&BW[(size_t)e * 8] = load_cvt8(w_out + (size_t)row * MID + col);
    }
    __syncthreads();

    const int rb = (blockIdx.x * 4 + wave) * 16;
    short8 A0 = *(const short8*)(om_bf + (size_t)(rb + l15) * MID + quad * 8);
    short8 A1 = *(const short8*)(om_bf + (size_t)(rb + l15) * MID + 32 + quad * 8);

    #pragma unroll 4
    for (int nt = 0; nt < 16; nt++) {
        short8 b0 = *(const short8*)&BW[(size_t)((nt * 2 + 0) * 64 + lane) * 8];
        short8 b1 = *(const short8*)&BW[(size_t)((nt * 2 + 1) * 64 + lane) * 8];
        f32x4 c = (f32x4){0.f, 0.f, 0.f, 0.f};
        c = MFMA(A0, b0, c);
        c = MFMA(A1, b1, c);
        #pragma unroll
        for (int r = 0; r < 4; r++) {
            size_t off = (size_t)(rb + quad * 4 + r) * INC + nt * 16 + l15;
            out[off] = c[r] + feats[off];
        }
    }
}

extern "C" void kernel_launch(void* const* d_in, const int* in_sizes, int n_in,
                              void* d_out, int out_size, void* d_ws, size_t ws_size,
                              hipStream_t stream)
{
    const float* feats = (const float*)d_in[0];
    const float* pos   = (const float*)d_in[1];
    const int*   idx   = (const int*)d_in[2];
    const float* w_in  = (const float*)d_in[3];
    const float* w_q   = (const float*)d_in[4];
    const float* b_q   = (const float*)d_in[5];
    const float* w_k   = (const float*)d_in[6];
    const float* b_k   = (const float*)d_in[7];
    const float* w_v   = (const float*)d_in[8];
    const float* b_v   = (const float*)d_in[9];
    const float* pe_w1 = (const float*)d_in[10];
    const float* pe_b1 = (const float*)d_in[11];
    const float* pe_g1 = (const float*)d_in[12];
    const float* pe_be1= (const float*)d_in[13];
    const float* pe_m1 = (const float*)d_in[14];
    const float* pe_v1 = (const float*)d_in[15];
    const float* pe_w2 = (const float*)d_in[16];
    const float* pe_b2 = (const float*)d_in[17];
    const float* pe_g2 = (const float*)d_in[18];
    const float* pe_be2= (const float*)d_in[19];
    const float* pe_m2 = (const float*)d_in[20];
    const float* pe_v2 = (const float*)d_in[21];
    const float* ga_w1 = (const float*)d_in[22];
    const float* ga_b1 = (const float*)d_in[23];
    const float* ga_g1 = (const float*)d_in[24];
    const float* ga_be1= (const float*)d_in[25];
    const float* ga_m1 = (const float*)d_in[26];
    const float* ga_v1 = (const float*)d_in[27];
    const float* ga_w2 = (const float*)d_in[28];
    const float* ga_b2 = (const float*)d_in[29];
    const float* ga_g2 = (const float*)d_in[30];
    const float* ga_be2= (const float*)d_in[31];
    const float* ga_m2 = (const float*)d_in[32];
    const float* ga_v2 = (const float*)d_in[33];
    const float* w_out = (const float*)d_in[34];

    char* ws = (char*)d_ws;
    short* q_bf  = (short*)(ws);                            // 8 MB
    short* k_bf  = (short*)(ws + (size_t) 8 * 1024 * 1024); // 8 MB
    short* v_bf  = (short*)(ws + (size_t)16 * 1024 * 1024); // 8 MB
    short* om_bf = (short*)(ws + (size_t)24 * 1024 * 1024); // 8 MB

    k_qkv<<<NPTS / 64, 256, 0, stream>>>(feats, w_in, w_q, b_q, w_k, b_k, w_v, b_v,
                                         q_bf, k_bf, v_bf);
    k_attn<<<NPTS / 32, 512, 0, stream>>>(pos, idx,
                                          (const unsigned short*)q_bf,
                                          (const unsigned short*)k_bf, (const unsigned short*)v_bf,
                                          pe_w1, pe_b1, pe_g1, pe_be1, pe_m1, pe_v1,
                                          pe_w2, pe_b2, pe_g2, pe_be2, pe_m2, pe_v2,
                                          ga_w1, ga_b1, ga_g1, ga_be1, ga_m1, ga_v1,
                                          ga_w2, ga_b2, ga_g2, ga_be2, ga_m2, ga_v2,
                                          om_bf);
    k_out<<<NPTS / 64, 256, 0, stream>>>((const unsigned short*)om_bf, w_out, feats, (float*)d_out);
}